// Round 9
// baseline (522.144 us; speedup 1.0000x reference)
//
#include <hip/hip_runtime.h>

// Subtractor50Bit: A - B via two's complement, N rows x 50 bits ({0,1} floats).
// out = [result (N*50 floats), borrow (N floats)].
//
// R8: copy-shaped occupancy test. Per-CU delivered BW has been pinned at
// ~10 GB/s across 7 structures (waves 3-21, in-flight 2-90KB, reg vs
// LDS-DMA, NT on/off), yet the float4-copy ubench does 24.6 GB/s/CU on
// this chip. The only variable tracking delivered BW across all points is
// the count of waves concurrently waiting on memory (copy: 32/CU @ ~100%
// duty). R8 keeps the twice-verified R2/R3 float2-ballot math BYTE-FOR-BYTE
// and changes only the shell:
//   - persistent grid-stride over 64-row tiles, one tile per WAVE per iter
//   - 2048 blocks x 256 thr = exactly 8 blocks/CU = 32 waves/CU, held for
//     the whole kernel (no dispatch ramp/drain)
//   - __launch_bounds__(256, 8) forces VGPR<=64 so all 8 waves/SIMD fit
//   - natural load/ballot interleave (no sched_barrier): per-wave stalls
//     are fine when 32 wave-queues keep the memory system fed
//   - plain stores (NT falsified in R7b: FETCH unchanged, dur +13%), no LDS
// Gates: VGPR<=64, Occupancy>=85%. Win: dur 152 -> 90-115us.
// Null at 30+ waves/CU => axis sweep exhausted => roofline call.

constexpr int BITS = 50;
constexpr unsigned long long MASK50 = (1ULL << BITS) - 1ULL;

__device__ inline unsigned long long shfl64(unsigned long long v, int src) {
    int lo = __shfl((int)(unsigned)(v & 0xffffffffULL), src, 64);
    int hi = __shfl((int)(unsigned)(v >> 32), src, 64);
    return ((unsigned long long)(unsigned)hi << 32) | (unsigned long long)(unsigned)lo;
}

// bit i -> bit 2i (valid for i < 32)
__device__ inline unsigned long long spread2(unsigned long long x) {
    x = (x | (x << 16)) & 0x0000FFFF0000FFFFULL;
    x = (x | (x << 8))  & 0x00FF00FF00FF00FFULL;
    x = (x | (x << 4))  & 0x0F0F0F0F0F0F0F0FULL;
    x = (x | (x << 2))  & 0x3333333333333333ULL;
    x = (x | (x << 1))  & 0x5555555555555555ULL;
    return x;
}

__global__ __launch_bounds__(256, 8) void Subtractor50Bit_kernel(
    const float* __restrict__ A, const float* __restrict__ B,
    float* __restrict__ out, int N)
{
    const int lane   = threadIdx.x & 63;
    const int wv     = threadIdx.x >> 6;
    const int lane31 = lane & 31;
    const bool isLo  = lane < 32;

    const long long nTiles     = (long long)N >> 6;          // full 64-row tiles
    const long long wavesTotal = (long long)gridDim.x * 4;

    for (long long tile = (long long)blockIdx.x * 4 + wv;
         tile < nTiles; tile += wavesTotal) {

        const long long eBase = tile * 64 * BITS;            // 3200 floats/tile
        const float2* pa = (const float2*)(A + eBase) + lane;
        const float2* pb = (const float2*)(B + eBase) + lane;

        // ---- Phase 1+2 interleaved: rolling loads + ballots (R2 form).
        // Chunk t covers elements [128t,128t+128):
        //   .x ballot = even-plane word t, .y ballot = odd-plane word t.
        // E-words parked in lanes 0..24, O-words in lanes 32..56.
        unsigned long long wa = 0, wb = 0;
        #pragma unroll
        for (int t = 0; t < 25; ++t) {
            float2 va = pa[t * 64];
            float2 vb = pb[t * 64];
            unsigned long long aE = __ballot(va.x != 0.0f);
            unsigned long long aO = __ballot(va.y != 0.0f);
            unsigned long long bE = __ballot(vb.x != 0.0f);
            unsigned long long bO = __ballot(vb.y != 0.0f);
            if (lane31 == t) {
                wa = isLo ? aE : aO;
                wb = isLo ? bE : bO;
            }
        }

        // ---- Phase 3: per-lane row assembly (verified R2/R3).
        // Row's even bits = even-plane window [25*lane, 25*lane+25).
        const int p0 = 25 * lane;
        const int w0 = p0 >> 6;
        const int sh = p0 & 63;

        unsigned long long aE0 = shfl64(wa, w0);
        unsigned long long aE1 = shfl64(wa, w0 + 1);   // src>24 holds 0 (safe)
        unsigned long long aO0 = shfl64(wa, 32 + w0);
        unsigned long long aO1 = shfl64(wa, 33 + w0);
        unsigned long long bE0 = shfl64(wb, w0);
        unsigned long long bE1 = shfl64(wb, w0 + 1);
        unsigned long long bO0 = shfl64(wb, 32 + w0);
        unsigned long long bO1 = shfl64(wb, 33 + w0);

        unsigned long long evA = aE0 >> sh, odA = aO0 >> sh;
        unsigned long long evB = bE0 >> sh, odB = bO0 >> sh;
        if (sh > 39) {               // window straddles two plane words
            const int c = 64 - sh;   // in [1,24] -> shifts well-defined
            evA |= aE1 << c; odA |= aO1 << c;
            evB |= bE1 << c; odB |= bO1 << c;
        }
        const unsigned long long M25 = (1ULL << 25) - 1ULL;
        evA &= M25; odA &= M25; evB &= M25; odB &= M25;

        unsigned long long av = spread2(evA) | (spread2(odA) << 1);
        unsigned long long bv = spread2(evB) | (spread2(odB) << 1);

        unsigned long long diff = (av - bv) & MASK50;  // A + ~B + 1 (mod 2^50)
        float borrow = (av < bv) ? 1.0f : 0.0f;        // 1 - carry_out

        // ---- Phase 4: packed 8B stores, coalesced (verified R2/R3).
        unsigned long long* po = (unsigned long long*)(out + eBase);
        #pragma unroll
        for (int j = 0; j < 25; ++j) {
            int q = j * 64 + lane;            // float2 index in [0,1600)
            int r = q / 25;                   // owning local row (magic-mul)
            int k = 2 * (q - r * 25);         // bit index within row
            unsigned long long dr = shfl64(diff, r);
            unsigned long long t2 = dr >> k;
            po[q] = ((t2 & 1ULL) ? 0x000000003F800000ULL : 0ULL)
                  | ((t2 & 2ULL) ? 0x3F80000000000000ULL : 0ULL);
        }
        // borrow segment: naturally coalesced
        out[(long long)N * BITS + tile * 64 + lane] = borrow;
    }

    // ---- remainder rows (N % 64 != 0 safety net): block 0, wave 0.
    if (blockIdx.x == 0 && wv == 0) {
        long long r = nTiles * 64 + lane;
        if (r < N) {
            unsigned long long av = 0, bv = 0;
            for (int k = 0; k < BITS; ++k) {
                av |= (unsigned long long)(A[r * BITS + k] != 0.0f) << k;
                bv |= (unsigned long long)(B[r * BITS + k] != 0.0f) << k;
            }
            unsigned long long diff = (av - bv) & MASK50;
            for (int k = 0; k < BITS; ++k)
                out[r * BITS + k] = (float)((diff >> k) & 1ULL);
            out[(long long)N * BITS + r] = (av < bv) ? 1.0f : 0.0f;
        }
    }
}

extern "C" void kernel_launch(void* const* d_in, const int* in_sizes, int n_in,
                              void* d_out, int out_size, void* d_ws, size_t ws_size,
                              hipStream_t stream) {
    const float* A = (const float*)d_in[0];
    const float* B = (const float*)d_in[1];
    float* out = (float*)d_out;
    const int N = in_sizes[0] / BITS;          // 1,000,000

    const long long nTiles = (long long)N >> 6;
    // 8 blocks/CU x 256 CUs = 2048 persistent blocks = 32 waves/CU,
    // the thread-slot maximum. Each wave grid-strides over ~1.9 tiles.
    long long want = (nTiles + 3) / 4;                 // enough waves for tiles
    if (want > 2048) want = 2048;
    if (want < 1) want = 1;
    Subtractor50Bit_kernel<<<(int)want, 256, 0, stream>>>(A, B, out, N);
}

// Round 10
// 436.793 us; speedup vs baseline: 1.1954x; 1.1954x over previous
//
#include <hip/hip_runtime.h>

// Subtractor50Bit: A - B via two's complement, N rows x 50 bits ({0,1} floats).
// out = [result (N*50 floats), borrow (N floats)].
//
// R9: R3 verbatim EXCEPT the 50 float2 input loads are NONTEMPORAL.
// Single-variable A/B against R3's verified 154.6us.
// Model (fits all 8 rounds): writes never allocate in the MALL (WRITE ==
// output size every round; explains R7b's NT-store null), so the 256MB L3
// holds only input lines; 400MB cycled through 256MB at non-LRU replacement
// -> ~51% hit rate (FETCH=195/400 exactly) with a RANDOMLY SCATTERED
// resident subset. The HBM read stream is therefore a random ~49% subsample
// of a sequential stream -> DRAM row-buffer efficiency ~0.42 -> 6.3 x 0.42
// ~= 2.6 TB/s == the observed 2.4-2.75 cap, immune to every CU-side knob.
// NT loads (no-allocate) decay the residency -> every rep reads the full
// 400MB SEQUENTIALLY at copy-like efficiency.
// Mechanism signature: FETCH 195 -> ~380-400MB.
// Win: dur 154 -> ~100-120us. FETCH flat => NT-load doesn't bypass MALL
// (roofline next). FETCH up but dur up => efficiency theory wrong (revert,
// roofline next).

constexpr int BITS = 50;
constexpr unsigned long long MASK50 = (1ULL << BITS) - 1ULL;

// clang-native vector: required by __builtin_nontemporal_load
// (HIP float2 is a struct); layout-identical to float2 (8B, 8B-aligned).
typedef float v2f __attribute__((ext_vector_type(2)));

__device__ inline unsigned long long shfl64(unsigned long long v, int src) {
    int lo = __shfl((int)(unsigned)(v & 0xffffffffULL), src, 64);
    int hi = __shfl((int)(unsigned)(v >> 32), src, 64);
    return ((unsigned long long)(unsigned)hi << 32) | (unsigned long long)(unsigned)lo;
}

// bit i -> bit 2i (valid for i < 32)
__device__ inline unsigned long long spread2(unsigned long long x) {
    x = (x | (x << 16)) & 0x0000FFFF0000FFFFULL;
    x = (x | (x << 8))  & 0x00FF00FF00FF00FFULL;
    x = (x | (x << 4))  & 0x0F0F0F0F0F0F0F0FULL;
    x = (x | (x << 2))  & 0x3333333333333333ULL;
    x = (x | (x << 1))  & 0x5555555555555555ULL;
    return x;
}

__global__ __launch_bounds__(256) void Subtractor50Bit_kernel(
    const float* __restrict__ A, const float* __restrict__ B,
    float* __restrict__ out, int N)
{
    const int lane = threadIdx.x & 63;
    const int wv   = threadIdx.x >> 6;
    const long long waveIdx = (long long)blockIdx.x * 4 + wv;
    const long long rowBase = waveIdx * 64;
    if (rowBase >= N) return;

    if (rowBase + 64 <= N) {
        // ---- full-wave fast path (64 rows, all lanes active) ----
        const long long eBase = rowBase * BITS;          // 3200 elements/wave
        const v2f* pa = (const v2f*)(A + eBase) + lane;
        const v2f* pb = (const v2f*)(B + eBase) + lane;

        // Phase 1: ALL loads issued first (independent, 512B/instr coalesced),
        // NONTEMPORAL: no MALL allocation -> sequential HBM read stream.
        v2f fa[25], fb[25];
        #pragma unroll
        for (int t = 0; t < 25; ++t) fa[t] = __builtin_nontemporal_load(pa + t * 64);
        #pragma unroll
        for (int t = 0; t < 25; ++t) fb[t] = __builtin_nontemporal_load(pb + t * 64);

        __builtin_amdgcn_sched_barrier(0);

        // Phase 2: ballots. Chunk t covers elements [128t, 128t+128):
        //   .x ballot = even-plane word t  (bit i = element 128t+2i)
        //   .y ballot = odd-plane  word t  (bit i = element 128t+2i+1)
        // E-words parked in lanes 0..24, O-words in lanes 32..56; others 0.
        unsigned long long wa = 0, wb = 0;
        const int  lane31 = lane & 31;
        const bool isLo   = lane < 32;
        #pragma unroll
        for (int t = 0; t < 25; ++t) {
            unsigned long long aE = __ballot(fa[t].x != 0.0f);
            unsigned long long aO = __ballot(fa[t].y != 0.0f);
            unsigned long long bE = __ballot(fb[t].x != 0.0f);
            unsigned long long bO = __ballot(fb[t].y != 0.0f);
            if (lane31 == t) {
                wa = isLo ? aE : aO;
                wb = isLo ? bE : bO;
            }
        }

        // Phase 3: per-lane row assembly; lane owns row (rowBase + lane).
        // Row's even bits = even-plane window [25*lane, 25*lane+25).
        const int p0 = 25 * lane;
        const int w0 = p0 >> 6;
        const int sh = p0 & 63;

        unsigned long long aE0 = shfl64(wa, w0);
        unsigned long long aE1 = shfl64(wa, w0 + 1);      // src>24 holds 0 (safe)
        unsigned long long aO0 = shfl64(wa, 32 + w0);
        unsigned long long aO1 = shfl64(wa, 33 + w0);
        unsigned long long bE0 = shfl64(wb, w0);
        unsigned long long bE1 = shfl64(wb, w0 + 1);
        unsigned long long bO0 = shfl64(wb, 32 + w0);
        unsigned long long bO1 = shfl64(wb, 33 + w0);

        unsigned long long evA = aE0 >> sh, odA = aO0 >> sh;
        unsigned long long evB = bE0 >> sh, odB = bO0 >> sh;
        if (sh > 39) {               // window straddles two plane words
            const int c = 64 - sh;   // in [1,24] here -> shifts well-defined
            evA |= aE1 << c; odA |= aO1 << c;
            evB |= bE1 << c; odB |= bO1 << c;
        }
        const unsigned long long M25 = (1ULL << 25) - 1ULL;
        evA &= M25; odA &= M25; evB &= M25; odB &= M25;

        unsigned long long av = spread2(evA) | (spread2(odA) << 1);
        unsigned long long bv = spread2(evB) | (spread2(odB) << 1);

        unsigned long long diff = (av - bv) & MASK50;     // A + ~B + 1 (mod 2^50)
        float borrow = (av < bv) ? 1.0f : 0.0f;           // 1 - carry_out

        // Phase 4: packed 8B stores, coalesced 512B/instr (plain stores;
        // NT-store was a measured regression and writes are already
        // no-allocate). float2 q covers elements [2q,2q+2), one row each.
        unsigned long long* po = (unsigned long long*)(out + eBase);
        #pragma unroll
        for (int j = 0; j < 25; ++j) {
            int q = j * 64 + lane;            // float2 index in [0,1600)
            int r = q / 25;                   // owning local row (magic-mul)
            int k = 2 * (q - r * 25);         // bit index within row
            unsigned long long dr = shfl64(diff, r);
            unsigned long long t2 = dr >> k;
            po[q] = ((t2 & 1ULL) ? 0x000000003F800000ULL : 0ULL)
                  | ((t2 & 2ULL) ? 0x3F80000000000000ULL : 0ULL);
        }
        // borrow segment: naturally coalesced
        out[(long long)N * BITS + rowBase + lane] = borrow;
    } else {
        // ---- scalar tail path (partial wave; N%64!=0 safety net) ----
        long long r = rowBase + lane;
        if (r < N) {
            unsigned long long av = 0, bv = 0;
            for (int k = 0; k < BITS; ++k) {
                av |= (unsigned long long)(A[r * BITS + k] != 0.0f) << k;
                bv |= (unsigned long long)(B[r * BITS + k] != 0.0f) << k;
            }
            unsigned long long diff = (av - bv) & MASK50;
            for (int k = 0; k < BITS; ++k)
                out[r * BITS + k] = (float)((diff >> k) & 1ULL);
            out[(long long)N * BITS + r] = (av < bv) ? 1.0f : 0.0f;
        }
    }
}

extern "C" void kernel_launch(void* const* d_in, const int* in_sizes, int n_in,
                              void* d_out, int out_size, void* d_ws, size_t ws_size,
                              hipStream_t stream) {
    const float* A = (const float*)d_in[0];
    const float* B = (const float*)d_in[1];
    float* out = (float*)d_out;
    const int N = in_sizes[0] / BITS;          // 1,000,000

    const int waves  = (N + 63) / 64;          // one wave per 64 rows
    const int blocks = (waves + 3) / 4;        // 4 waves per 256-thread block
    Subtractor50Bit_kernel<<<blocks, 256, 0, stream>>>(A, B, out, N);
}